// Round 5
// baseline (377.525 us; speedup 1.0000x reference)
//
#include <hip/hip_runtime.h>
#include <math.h>

#define DIM   4096
#define NEXP  64
#define MB    16               // tokens per block
#define KC    128              // k per LDS stage (elements)
#define NST   (DIM / KC)       // 32 stages

typedef _Float16 f16x8 __attribute__((ext_vector_type(8)));
typedef _Float16 f16x4 __attribute__((ext_vector_type(4)));
typedef float    f32x4 __attribute__((ext_vector_type(4)));

// ---- Kernel 0: pack W -> fp16 hi/lo planes in MFMA B-fragment order --------
// wp[nt(4)][ck(128)][lane(64)][j(8)]; lane = quad*16 + n; element = W[nt*16+n][ck*32+quad*8+j]
__global__ __launch_bounds__(256)
void pack_w_kernel(const float* __restrict__ W,
                   _Float16* __restrict__ wph, _Float16* __restrict__ wpl) {
    const int flat = blockIdx.x * 256 + threadIdx.x;   // nt*8192 + ck*64 + lane
    const int lane = flat & 63;
    const int ck   = (flat >> 6) & 127;
    const int nt   = flat >> 13;
    const int e    = nt * 16 + (lane & 15);
    const int k0   = ck * 32 + (lane >> 4) * 8;
    const float* src = W + ((size_t)e << 12) + k0;
    float4 v0 = *(const float4*)(src);
    float4 v1 = *(const float4*)(src + 4);
    float vv[8] = {v0.x, v0.y, v0.z, v0.w, v1.x, v1.y, v1.z, v1.w};
    f16x8 hi, lo;
#pragma unroll
    for (int i = 0; i < 8; ++i) {
        _Float16 hh = (_Float16)vv[i];
        hi[i] = hh;
        lo[i] = (_Float16)(vv[i] - (float)hh);   // Sterbenz-exact residual
    }
    *(f16x8*)(wph + (size_t)flat * 8) = hi;
    *(f16x8*)(wpl + (size_t)flat * 8) = lo;
}

// ---- Kernel 1: fused gate. 16 tokens/block, wave = 16-expert n-group -------
// C = Ah*Bh + Al*Bh + Ah*Bl (fp32-accurate). h prefetched 2 stages deep in
// regs; B one stage deep; A LDS XOR-swizzled (16B-block ^ row), double-buffered.
__global__ __launch_bounds__(256, 4)
void gate_mfma_kernel(const float* __restrict__ h,
                      const _Float16* __restrict__ wph,
                      const _Float16* __restrict__ wpl,
                      float* __restrict__ out, int n_tokens) {
    __shared__ _Float16 Ah[2][MB * KC];     // 8 KB
    __shared__ _Float16 Al[2][MB * KC];     // 8 KB
    __shared__ float    lg[MB][NEXP + 4];   // 4.3 KB  -> 20.3 KB total

    const int tid  = threadIdx.x;
    const int lane = tid & 63;
    const int wv   = __builtin_amdgcn_readfirstlane(tid >> 6);  // n-group 0..3
    const int l15  = lane & 15;
    const int quad = lane >> 4;
    const int t0   = blockIdx.x * MB;

    // h staging map: 16 tok x 128 k = 512 float4 / 256 thr = 2 each
    int s_t[2], s_f4[2];
#pragma unroll
    for (int d = 0; d < 2; ++d) {
        int flat = d * 256 + tid;
        s_t[d]  = flat >> 5;     // token row 0..15
        s_f4[d] = flat & 31;     // float4 index in row (k = 4*f4)
    }
    const float* hrow0 = h + (size_t)(t0 + s_t[0]) * DIM + 4 * s_f4[0];
    const float* hrow1 = h + (size_t)(t0 + s_t[1]) * DIM + 4 * s_f4[1];

    // 2-deep h prefetch: st[p] holds stage (c with c&1==p)
    float4 st[2][2];
    st[0][0] = *(const float4*)(hrow0);
    st[0][1] = *(const float4*)(hrow1);
    st[1][0] = *(const float4*)(hrow0 + KC);
    st[1][1] = *(const float4*)(hrow1 + KC);

    // B fragment base; 32-k chunk stride = 512 halves
    const _Float16* bph = wph + ((size_t)(wv * 128) * 64 + lane) * 8;
    const _Float16* bpl = wpl + ((size_t)(wv * 128) * 64 + lane) * 8;
    f16x8 Bh[2][4], Bl[2][4];
#pragma unroll
    for (int s = 0; s < 4; ++s) {
        Bh[0][s] = *(const f16x8*)(bph + s * 512);
        Bl[0][s] = *(const f16x8*)(bpl + s * 512);
    }

    f32x4 acc = {0.f, 0.f, 0.f, 0.f};

#pragma unroll 2
    for (int c = 0; c < NST; ++c) {
        const int buf = c & 1;
        // convert fp32 -> hi/lo, swizzled LDS write (uniform banks, free)
#pragma unroll
        for (int d = 0; d < 2; ++d) {
            float4 v = st[buf][d];
            _Float16 a0 = (_Float16)v.x, a1 = (_Float16)v.y,
                     a2 = (_Float16)v.z, a3 = (_Float16)v.w;
            f16x4 hh = {a0, a1, a2, a3};
            f16x4 ll = {(_Float16)(v.x - (float)a0), (_Float16)(v.y - (float)a1),
                        (_Float16)(v.z - (float)a2), (_Float16)(v.w - (float)a3)};
            int t = s_t[d], f4 = s_f4[d], b = f4 >> 1;
            int addr = t * KC + (((b ^ t) & 15) << 3) + ((f4 & 1) << 2);
            *(f16x4*)(&Ah[buf][addr]) = hh;
            *(f16x4*)(&Al[buf][addr]) = ll;
        }
        __syncthreads();

        // prefetch h two stages ahead (keeps HBM queue full)
        if (c + 2 < NST) {
            const int kn = (c + 2) * KC;
            st[buf][0] = *(const float4*)(hrow0 + kn);
            st[buf][1] = *(const float4*)(hrow1 + kn);
        }
        // prefetch B one stage ahead (L2-hot)
        if (c + 1 < NST) {
            const int nb = (c + 1) & 1;
            const size_t coff = (size_t)(c + 1) * 4 * 512;
#pragma unroll
            for (int s = 0; s < 4; ++s) {
                Bh[nb][s] = *(const f16x8*)(bph + coff + s * 512);
                Bl[nb][s] = *(const f16x8*)(bpl + coff + s * 512);
            }
        }

#pragma unroll
        for (int s = 0; s < 4; ++s) {
            const int bsw = (((4 * s + quad) ^ l15) & 15) << 3;  // swizzled 16B block
            f16x8 ah = *(const f16x8*)(&Ah[buf][l15 * KC + bsw]);
            f16x8 al = *(const f16x8*)(&Al[buf][l15 * KC + bsw]);
            f16x8 bh = Bh[buf][s], bl = Bl[buf][s];
            acc = __builtin_amdgcn_mfma_f32_16x16x32_f16(ah, bh, acc, 0, 0, 0);
            acc = __builtin_amdgcn_mfma_f32_16x16x32_f16(al, bh, acc, 0, 0, 0);
            acc = __builtin_amdgcn_mfma_f32_16x16x32_f16(ah, bl, acc, 0, 0, 0);
        }
        // double-buffered: next iteration's barrier protects buffer reuse
    }

    // ---- epilogue: C/D layout col(expert)=lane&15, row(token)=quad*4+r ----
#pragma unroll
    for (int r = 0; r < 4; ++r)
        lg[4 * quad + r][wv * 16 + l15] = acc[r];
    __syncthreads();

    if (tid < MB) {
        const float* row = lg[tid];
        float m = -INFINITY;
#pragma unroll 8
        for (int e = 0; e < NEXP; ++e) m = fmaxf(m, row[e]);
        float z = 0.0f, b1 = -INFINITY, b2 = -INFINITY;
        int i1 = 0, i2 = 0;
        for (int e = 0; e < NEXP; ++e) {
            float v = row[e];
            z += expf(v - m);
            if (v > b1)      { b2 = b1; i2 = i1; b1 = v; i1 = e; }
            else if (v > b2) { b2 = v; i2 = e; }
        }
        float g1 = expf(b1 - m), g2 = expf(b2 - m);
        float w1 = g1 / z, w2 = g2 / z;
        float ssum = w1 + w2 + 1e-9f;
        int t = t0 + tid;
        *(float2*)(out + 2 * t) = make_float2(w1 / ssum, w2 / ssum);
        *(float2*)(out + 2 * n_tokens + 2 * t) = make_float2((float)i1, (float)i2);
    }
}

extern "C" void kernel_launch(void* const* d_in, const int* in_sizes, int n_in,
                              void* d_out, int out_size, void* d_ws, size_t ws_size,
                              hipStream_t stream) {
    const float* h = (const float*)d_in[0];
    const float* W = (const float*)d_in[1];
    float* out = (float*)d_out;
    const int n_tokens = in_sizes[0] / DIM;        // 16384

    _Float16* wph = (_Float16*)d_ws;               // 512 KB packed hi
    _Float16* wpl = wph + (size_t)NEXP * DIM;      // 512 KB packed lo

    pack_w_kernel<<<(NEXP * DIM / 8) / 256, 256, 0, stream>>>(W, wph, wpl);
    gate_mfma_kernel<<<n_tokens / MB, 256, 0, stream>>>(h, wph, wpl, out, n_tokens);
}